// Round 8
// baseline (577.450 us; speedup 1.0000x reference)
//
#include <hip/hip_runtime.h>
#include <math.h>

#define INV_SQRT1P 0.99999500003749968754f   // 1/sqrt(1+1e-5)

typedef short v8s  __attribute__((ext_vector_type(8)));
typedef float v16f __attribute__((ext_vector_type(16)));

static __device__ __forceinline__ float lrelu(float f){ return f >= 0.0f ? f : 0.2f*f; }

// count of set bits in m strictly below this lane
static __device__ __forceinline__ int lanecnt_below(unsigned long long m){
  int c = __builtin_amdgcn_mbcnt_lo((unsigned)m, 0u);
  return __builtin_amdgcn_mbcnt_hi((unsigned)(m >> 32), c);
}

// ---------------- extract channels: feat (8,131,1024) -> rows [boff*1024..) (N,Cout) ----
__global__ void k_extract(const float* __restrict__ f, float* __restrict__ out, int c0, int Cout, int boff){
  int i = blockIdx.x*256 + threadIdx.x;
  int total = 8*Cout*1024;
  if (i >= total) return;
  int n  = i & 1023;
  int bc = i >> 10;
  int c  = bc % Cout;
  int b  = bc / Cout;
  out[((size_t)(((b+boff)<<10)+n))*Cout + c] = f[((size_t)(b*131 + c0 + c) << 10) + n];
}

// ---------------- fused pack: wpack blocks first, then X-pack blocks (with row xx) ----
__global__ __launch_bounds__(256) void k_pw(const float* __restrict__ X,
    unsigned short* __restrict__ PH, unsigned short* __restrict__ PL,
    float* __restrict__ xxout, const float* __restrict__ Wm,
    unsigned short* __restrict__ PWH, unsigned short* __restrict__ PWL,
    int C, int Kp, int O, int nwblk){
  int nkc = Kp >> 4;
  if ((int)blockIdx.x < nwblk){
    int gid = blockIdx.x*256 + threadIdx.x;
    int nchunk = (2*O/32)*nkc;
    if (gid >= nchunk*64) return;
    int lane = gid & 63;
    int chunk = gid >> 6;
    int jb = chunk / nkc, kc = chunk - jb*nkc;
    int j = jb*32 + (lane & 31);
    int k0 = kc*16 + ((lane>>5)<<3);
    unsigned short h[8], lo[8];
    #pragma unroll
    for (int t=0;t<8;t++){
      int k = k0 + t;
      float x = 0.f;
      if (k < C) x = (j < O) ? Wm[(size_t)j*2*C + k] : Wm[(size_t)(j-O)*2*C + C + k];
      unsigned u = __float_as_uint(x);
      unsigned h16 = (u + 0x7fffu + ((u>>16)&1u)) >> 16;
      float hf = __uint_as_float(h16 << 16);
      float lf = x - hf;
      unsigned ul = __float_as_uint(lf);
      unsigned l16 = (ul + 0x7fffu + ((ul>>16)&1u)) >> 16;
      h[t] = (unsigned short)h16; lo[t] = (unsigned short)l16;
    }
    size_t o = (size_t)chunk*512 + lane*8;
    *(v8s*)(PWH + o) = *(v8s*)h;
    *(v8s*)(PWL + o) = *(v8s*)lo;
  } else {
    int gid = (blockIdx.x - nwblk)*256 + threadIdx.x;   // grid exact: 512*nkc*64 threads
    int lane = gid & 63;
    int chunk = gid >> 6;
    int rb = chunk / nkc, kc = chunk - rb*nkc;
    int row = rb*32 + (lane & 31);
    int k0 = kc*16 + ((lane>>5)<<3);
    unsigned short h[8], lo[8];
    const float* Xr = X + (size_t)row*C;
    #pragma unroll
    for (int j=0;j<8;j++){
      int k = k0 + j;
      float x = (k < C) ? Xr[k] : 0.f;
      unsigned u = __float_as_uint(x);
      unsigned h16 = (u + 0x7fffu + ((u>>16)&1u)) >> 16;
      float hf = __uint_as_float(h16 << 16);
      float lf = x - hf;
      unsigned ul = __float_as_uint(lf);
      unsigned l16 = (ul + 0x7fffu + ((ul>>16)&1u)) >> 16;
      h[j] = (unsigned short)h16; lo[j] = (unsigned short)l16;
    }
    size_t o = (size_t)chunk*512 + lane*8;
    *(v8s*)(PH + o) = *(v8s*)h;
    *(v8s*)(PL + o) = *(v8s*)lo;
    if (kc == 0 && (lane & 32) == 0){
      float s = 0.f;
      for (int c=0;c<C;c++) s += Xr[c]*Xr[c];    // ascending order == old k_xx
      xxout[row] = s;
    }
  }
}

// ---------------- merged Y-GEMM + distance/top-20 ----------------
// First nymf blocks: Y = X.Wp^T. Remaining 512: dtk (round-3 structure) with
// short-chain selection: tau via 4-bit radix (8 steps x 15 independent ballots),
// compaction via hoisted independent ballots + SALU prefix, exact 20th via
// 2-bit radix (16 steps). Search-step chain count per phase: ~96 -> ~26.
__global__ __launch_bounds__(512) void k_dy(const unsigned short* __restrict__ PH,
    const unsigned short* __restrict__ PL, const unsigned short* __restrict__ PWH,
    const unsigned short* __restrict__ PWL, const float* __restrict__ xx,
    int* __restrict__ idx, float* __restrict__ Y, int Kp, int N, int npair, int nymf){
  __shared__ float Sl[16][1024];          // 64 KB
  int wave = threadIdx.x >> 6;
  int l = threadIdx.x & 63;
  int nkc = Kp >> 4;

  if ((int)blockIdx.x < nymf){
    // ---- ymf part: gw = blockIdx*8 + wave covers (mt, pair) ----
    int gw = blockIdx.x*8 + wave;
    int mt = gw / npair;
    int pair = gw - mt*npair;
    int jb0 = pair*2, jb1 = pair*2 + 1;
    size_t ao  = ((size_t)mt*nkc)*512 + l*8;
    size_t b0o = ((size_t)jb0*nkc)*512 + l*8;
    size_t b1o = ((size_t)jb1*nkc)*512 + l*8;
    v16f acc0, acc1;
    #pragma unroll
    for (int i=0;i<16;i++){ acc0[i] = 0.f; acc1[i] = 0.f; }
    for (int kc=0; kc<nkc; kc++){
      v8s Ah  = *(const v8s*)(PH + ao);
      v8s Al  = *(const v8s*)(PL + ao);
      v8s B0h = *(const v8s*)(PWH + b0o);
      v8s B0l = *(const v8s*)(PWL + b0o);
      v8s B1h = *(const v8s*)(PWH + b1o);
      v8s B1l = *(const v8s*)(PWL + b1o);
      acc0 = __builtin_amdgcn_mfma_f32_32x32x16_bf16(Ah, B0h, acc0, 0, 0, 0);
      acc1 = __builtin_amdgcn_mfma_f32_32x32x16_bf16(Ah, B1h, acc1, 0, 0, 0);
      acc0 = __builtin_amdgcn_mfma_f32_32x32x16_bf16(Ah, B0l, acc0, 0, 0, 0);
      acc1 = __builtin_amdgcn_mfma_f32_32x32x16_bf16(Ah, B1l, acc1, 0, 0, 0);
      acc0 = __builtin_amdgcn_mfma_f32_32x32x16_bf16(Al, B0h, acc0, 0, 0, 0);
      acc1 = __builtin_amdgcn_mfma_f32_32x32x16_bf16(Al, B1h, acc1, 0, 0, 0);
      ao += 512; b0o += 512; b1o += 512;
    }
    int rbase = mt*32;
    int c0 = pair*64 + (l & 31), c1 = c0 + 32;
    #pragma unroll
    for (int r=0;r<16;r++){
      int rl_ = (r&3) + ((r>>2)<<3) + ((l>>5)<<2);
      float* dst = Y + (size_t)(rbase + rl_)*N;
      dst[c0] = acc0[r];
      dst[c1] = acc1[r];
    }
    return;
  }

  // ---- dtk part ----
  int rb = blockIdx.x - nymf;             // rowblock 0..511
  int batch = rb >> 5;
  const float* xxb = xx + (batch<<10);
  int rbase_local = (rb & 31)*32;

  v16f acc[4];
  #pragma unroll
  for (int i=0;i<4;i++){
    #pragma unroll
    for (int j=0;j<16;j++) acc[i][j] = 0.f;
  }
  #pragma unroll
  for (int pp=0; pp<2; pp++){
    int pair = wave*2 + pp;
    size_t a   = ((size_t)rb*nkc)*512 + l*8;
    size_t b0o = ((size_t)(batch*32 + 2*pair)*nkc)*512 + l*8;
    size_t b1o = b0o + (size_t)nkc*512;
    for (int kc=0; kc<nkc; kc++){
      v8s Ah  = *(const v8s*)(PH + a);
      v8s Al  = *(const v8s*)(PL + a);
      v8s B0h = *(const v8s*)(PH + b0o);
      v8s B0l = *(const v8s*)(PL + b0o);
      v8s B1h = *(const v8s*)(PH + b1o);
      v8s B1l = *(const v8s*)(PL + b1o);
      acc[2*pp]   = __builtin_amdgcn_mfma_f32_32x32x16_bf16(Ah, B0h, acc[2*pp],   0, 0, 0);
      acc[2*pp+1] = __builtin_amdgcn_mfma_f32_32x32x16_bf16(Ah, B1h, acc[2*pp+1], 0, 0, 0);
      acc[2*pp]   = __builtin_amdgcn_mfma_f32_32x32x16_bf16(Ah, B0l, acc[2*pp],   0, 0, 0);
      acc[2*pp+1] = __builtin_amdgcn_mfma_f32_32x32x16_bf16(Ah, B1l, acc[2*pp+1], 0, 0, 0);
      acc[2*pp]   = __builtin_amdgcn_mfma_f32_32x32x16_bf16(Al, B0h, acc[2*pp],   0, 0, 0);
      acc[2*pp+1] = __builtin_amdgcn_mfma_f32_32x32x16_bf16(Al, B1h, acc[2*pp+1], 0, 0, 0);
      a += 512; b0o += 512; b1o += 512;
    }
  }

  #pragma unroll
  for (int h=0; h<2; h++){
    // ---- write rows [16h,16h+16) of the tile into LDS with neg_d epilogue ----
    #pragma unroll
    for (int pp=0; pp<2; pp++){
      int pair = wave*2 + pp;
      int c0 = pair*64 + (l & 31), c1 = c0 + 32;
      float xc0 = xxb[c0], xc1 = xxb[c1];
      #pragma unroll
      for (int r = 0; r < 8; r++){
        int rr = h*8 + r;
        int rl = (rr&3) + (((rr>>2)&1)<<3) + ((l>>5)<<2);  // 0..15
        float xr = xxb[rbase_local + h*16 + rl];
        Sl[rl][c0] = 2.f*acc[2*pp][rr]   - xr - xc0;
        Sl[rl][c1] = 2.f*acc[2*pp+1][rr] - xr - xc1;
      }
    }
    __syncthreads();
    // ---- exact top-20: 2 rows per wave, half-waves in parallel ----
    {
      int hi = l >> 5;
      int li = l & 31;
      int rloc = wave*2 + hi;
      int grow = rb*32 + h*16 + rloc;
      int out_base = grow*20;
      unsigned long long hm = hi ? 0xFFFFFFFF00000000ull : 0x00000000FFFFFFFFull;

      // 32 values per lane; index m = li + 32*j (slot order == ascending index)
      unsigned kv[32];
      #pragma unroll
      for (int j=0;j<32;j++){
        unsigned u = __float_as_uint(Sl[rloc][li + 32*j]);
        kv[j] = (u & 0x80000000u) ? ~u : (u | 0x80000000u);
      }

      unsigned lmax = kv[0];
      #pragma unroll
      for (int j=1;j<32;j++) lmax = lmax > kv[j] ? lmax : kv[j];

      // tau = 20th-largest lane-max in this half; 4-bit radix, 8 steps,
      // 15 independent ballots per step (chain link = 1 ballot + select cascade)
      unsigned tau = 0u;
      #pragma unroll
      for (int bit=28; bit>=0; bit-=4){
        unsigned long long Mk[15];
        #pragma unroll
        for (int k=0;k<15;k++) Mk[k] = __ballot(lmax >= (tau | ((unsigned)(k+1) << bit)));
        unsigned best = 0u;
        #pragma unroll
        for (int k=0;k<15;k++){
          int n = hi ? __popc((unsigned)(Mk[k] >> 32)) : __popc((unsigned)Mk[k]);
          best = (n >= 20) ? (unsigned)(k+1) : best;
        }
        tau |= best << bit;
      }

      // compaction: independent ballots (2 groups of 16) + SALU prefix
      unsigned long long* sl = (unsigned long long*)&Sl[rloc][0];
      sl[li] = 0ull; sl[li+32] = 0ull;
      int b2 = 0;
      #pragma unroll
      for (int g=0; g<2; g++){
        unsigned long long Mg[16];
        #pragma unroll
        for (int j=0;j<16;j++) Mg[j] = __ballot(kv[g*16+j] >= tau) & hm;
        #pragma unroll
        for (int j=0;j<16;j++){
          if (kv[g*16+j] >= tau){
            int s = b2 + lanecnt_below(Mg[j]);
            if (s < 64) sl[s] = ((unsigned long long)kv[g*16+j] << 32) | (unsigned)(li + 32*(g*16+j));
          }
          b2 += __popcll(Mg[j]);
        }
      }

      if (b2 <= 64){
        unsigned long long pk0 = sl[li], pk1 = sl[li+32];  // empty slots: key 0
        unsigned k0 = (unsigned)(pk0 >> 32), k1 = (unsigned)(pk1 >> 32);
        // exact 20th-largest among survivors; 2-bit radix, 16 steps
        unsigned vcur = 0u;
        #pragma unroll
        for (int bit=30; bit>=0; bit-=2){
          unsigned q1 = vcur | (1u << bit);
          unsigned q2 = vcur | (2u << bit);
          unsigned q3 = vcur | (3u << bit);
          unsigned long long A1 = __ballot(k0 >= q1), B1 = __ballot(k1 >= q1);
          unsigned long long A2 = __ballot(k0 >= q2), B2 = __ballot(k1 >= q2);
          unsigned long long A3 = __ballot(k0 >= q3), B3 = __ballot(k1 >= q3);
          int n1 = hi ? (__popc((unsigned)(A1>>32)) + __popc((unsigned)(B1>>32)))
                      : (__popc((unsigned)A1) + __popc((unsigned)B1));
          int n2 = hi ? (__popc((unsigned)(A2>>32)) + __popc((unsigned)(B2>>32)))
                      : (__popc((unsigned)A2) + __popc((unsigned)B2));
          int n3 = hi ? (__popc((unsigned)(A3>>32)) + __popc((unsigned)(B3>>32)))
                      : (__popc((unsigned)A3) + __popc((unsigned)B3));
          vcur = (n3 >= 20) ? q3 : (n2 >= 20) ? q2 : (n1 >= 20) ? q1 : vcur;
        }
        unsigned long long G0 = __ballot(k0 > vcur) & hm;
        unsigned long long G1 = __ballot(k1 > vcur) & hm;
        int ng0 = __popcll(G0);
        int c1  = ng0 + __popcll(G1);
        if (k0 > vcur) idx[out_base + lanecnt_below(G0)] = (int)(pk0 & 0xffffffffu);
        if (k1 > vcur) idx[out_base + ng0 + lanecnt_below(G1)] = (int)(pk1 & 0xffffffffu);
        unsigned long long E0 = __ballot(k0 == vcur) & hm;
        unsigned long long E1 = __ballot(k1 == vcur) & hm;
        int ne0 = __popcll(E0);
        if (k0 == vcur){ int s = c1 + lanecnt_below(E0); if (s < 20) idx[out_base + s] = (int)(pk0 & 0xffffffffu); }
        if (k1 == vcur){ int s = c1 + ne0 + lanecnt_below(E1); if (s < 20) idx[out_base + s] = (int)(pk1 & 0xffffffffu); }
      } else {
        // rare (near-degenerate ties): exact search over all 1024 values
        unsigned cur = 0u;
        #pragma unroll 1
        for (int bit=31; bit>=0; --bit){
          unsigned cand = cur | (1u << bit);
          int lc = 0;
          #pragma unroll
          for (int j=0;j<32;j++) lc += (kv[j] >= cand) ? 1 : 0;
          #pragma unroll
          for (int off=1; off<32; off<<=1) lc += __shfl_xor(lc, off, 64);  // within-half sum
          cur = (lc >= 20) ? cand : cur;
        }
        int bse = 0;
        #pragma unroll 1
        for (int j=0;j<32;j++){
          unsigned long long Mg2 = __ballot(kv[j] > cur) & hm;
          if (kv[j] > cur){ int s = bse + lanecnt_below(Mg2); idx[out_base + s] = li + 32*j; }
          bse += __popcll(Mg2);
        }
        #pragma unroll 1
        for (int j=0;j<32;j++){
          unsigned long long Me = __ballot(kv[j] == cur) & hm;
          if (kv[j] == cur){ int s = bse + lanecnt_below(Me); if (s < 20) idx[out_base + s] = li + 32*j; }
          bse += __popcll(Me);
          if (bse >= 20) break;
        }
      }
    }
    __syncthreads();
  }
}

// ---------------- thin NT GEMM (kept for the emb combine) ----------------
__global__ __launch_bounds__(256) void k_gthin(
    const float* __restrict__ Am, const float* __restrict__ Bm, float* __restrict__ Om,
    int K, int ldo, int wmode, const float* __restrict__ p1, const float* __restrict__ p2, int ep)
{
  __shared__ float As[64][33];
  __shared__ float Bs[64][68];
  int tid = threadIdx.x;
  int tx = tid & 15, ty = tid >> 4;
  int rbase = blockIdx.y*32, cbase = blockIdx.x*64;
  float acc[2][4];
  #pragma unroll
  for (int i=0;i<2;i++){ acc[i][0]=0.f; acc[i][1]=0.f; acc[i][2]=0.f; acc[i][3]=0.f; }

  for (int c0=0; c0<K; c0+=64){
    int cw = K - c0; if (cw > 64) cw = 64;
    #pragma unroll
    for (int p=0; p<2; p++){
      int idx = p*256 + tid;
      int kq = idx & 15, row = idx >> 4;
      const float* src = Am + (size_t)(rbase+row)*K + c0 + kq*4;
      float4 v = {0.f,0.f,0.f,0.f};
      if (kq*4 + 4 <= cw) v = *(const float4*)src;
      else {
        if (kq*4+0 < cw) v.x = src[0];
        if (kq*4+1 < cw) v.y = src[1];
        if (kq*4+2 < cw) v.z = src[2];
        if (kq*4+3 < cw) v.w = src[3];
      }
      As[kq*4+0][row]=v.x; As[kq*4+1][row]=v.y; As[kq*4+2][row]=v.z; As[kq*4+3][row]=v.w;
    }
    #pragma unroll
    for (int p=0; p<4; p++){
      int idx = p*256 + tid;
      int kq = idx & 15, col = idx >> 4;
      int j = cbase + col;
      const float* src = (wmode > 0)
          ? ((j < wmode) ? Bm + (size_t)j*2*K + c0 + kq*4
                         : Bm + (size_t)(j-wmode)*2*K + K + c0 + kq*4)
          : Bm + (size_t)j*K + c0 + kq*4;
      float4 v = {0.f,0.f,0.f,0.f};
      if (kq*4 + 4 <= cw) v = *(const float4*)src;
      else {
        if (kq*4+0 < cw) v.x = src[0];
        if (kq*4+1 < cw) v.y = src[1];
        if (kq*4+2 < cw) v.z = src[2];
        if (kq*4+3 < cw) v.w = src[3];
      }
      int swb = (kq & 14) << 1;
      int cs = col ^ swb;
      Bs[kq*4+0][cs]=v.x; Bs[kq*4+1][cs]=v.y; Bs[kq*4+2][cs]=v.z; Bs[kq*4+3][cs]=v.w;
    }
    __syncthreads();
    for (int k=0;k<cw;k++){
      int sw = ((k>>3)&7)<<2;
      float a0 = As[k][ty*2], a1 = As[k][ty*2+1];
      float b[4];
      *(float4*)b = *(const float4*)&Bs[k][(tx*4) ^ sw];
      acc[0][0]+=a0*b[0]; acc[0][1]+=a0*b[1]; acc[0][2]+=a0*b[2]; acc[0][3]+=a0*b[3];
      acc[1][0]+=a1*b[0]; acc[1][1]+=a1*b[1]; acc[1][2]+=a1*b[2]; acc[1][3]+=a1*b[3];
    }
    __syncthreads();
  }
  #pragma unroll
  for (int i=0;i<2;i++){
    int r = rbase + ty*2 + i;
    float o[4];
    #pragma unroll
    for (int j=0;j<4;j++){
      int cc = cbase + tx*4 + j;
      float v = acc[i][j];
      if (ep == 1) v = lrelu(p1[cc]*v*INV_SQRT1P + p2[cc]);
      o[j] = v;
    }
    *(float4*)(Om + (size_t)r*ldo + cbase + tx*4) = *(float4*)o;
  }
}

// ---------------- edge epilogue, multi-row blocks (256 threads) ----------------
__global__ __launch_bounds__(256) void k_edge(const float* __restrict__ Y, const int* __restrict__ idx,
    const float* __restrict__ g, const float* __restrict__ bias,
    float* __restrict__ out, int O, int ldo, int ooff){
  int rpb = 256/O;
  int rloc = threadIdx.x/O;
  int o = threadIdx.x - rloc*O;
  int row = blockIdx.x*rpb + rloc;
  int b = row >> 10;
  __shared__ int js[4][20];
  int nj = rpb*20;
  if (threadIdx.x < nj) js[threadIdx.x/20][threadIdx.x%20] = idx[(blockIdx.x*rpb)*20 + threadIdx.x];
  __syncthreads();
  int O2 = O*2;
  float y1c = Y[(size_t)row*O2 + o];
  float d   = Y[(size_t)row*O2 + O + o] - y1c;
  float sc  = g[o] * INV_SQRT1P;
  float bb  = bias[o];
  const float* Yb = Y + ((size_t)(b<<10))*O2;
  float best = -1e38f;
  #pragma unroll
  for (int k=0;k<20;k++){
    float f = sc * (Yb[(size_t)js[rloc][k]*O2 + o] + d) + bb;
    best = fmaxf(best, lrelu(f));
  }
  out[(size_t)row*ldo + ooff + o] = best;
}

// ---------------- attention (16 batches): fused mean + gc ----------------
__global__ __launch_bounds__(1024) void k_meangc(const float* __restrict__ emb,
     const float* __restrict__ att_w, float* __restrict__ gc){
  int b = blockIdx.x; int f = threadIdx.x & 127; int ny = threadIdx.x >> 7;
  const float* e = emb + ((size_t)(b<<10) + ny*128)*128 + f;
  float s = 0.f;
  for (int n=0;n<128;n++) s += e[n*128];
  __shared__ float red[8][128];
  __shared__ float mr[128];
  red[ny][f] = s;
  __syncthreads();
  if (ny == 0){
    float t = 0.f;
    #pragma unroll
    for (int i=0;i<8;i++) t += red[i][f];
    mr[f] = t * (1.0f/1024.0f);
  }
  __syncthreads();
  if (threadIdx.x < 128){
    int g = threadIdx.x;
    float s2 = 0.f;
    for (int ff=0; ff<128; ff++) s2 += mr[ff]*att_w[ff*128+g];
    gc[b*128+g] = tanhf(s2);
  }
}

__global__ __launch_bounds__(64) void k_sc(const float* __restrict__ emb, const float* __restrict__ gc,
     float* __restrict__ sc, float* __restrict__ attout){
  int row = blockIdx.x; int l = threadIdx.x; int b = row >> 10;
  const float* e  = emb + (size_t)row*128;
  const float* gb = gc + b*128;
  float p = e[l]*gb[l] + e[l+64]*gb[l+64];
  #pragma unroll
  for (int off=32; off>0; off>>=1) p += __shfl_xor(p, off, 64);
  if (l == 0){
    float s = 1.0f/(1.0f + expf(-p));
    sc[row] = s;
    attout[row] = s;
  }
}

__global__ __launch_bounds__(1024) void k_pool(const float* __restrict__ emb, const float* __restrict__ sc,
     float* __restrict__ ep){
  int b = blockIdx.x; int f = threadIdx.x & 127; int ny = threadIdx.x >> 7;
  const float* e  = emb + ((size_t)(b<<10) + ny*128)*128 + f;
  const float* sb = sc + (b<<10) + ny*128;
  float s = 0.f;
  for (int n=0;n<128;n++) s += e[n*128]*sb[n];
  __shared__ float red[8][128];
  red[ny][f] = s;
  __syncthreads();
  if (ny == 0){
    float t = 0.f;
    #pragma unroll
    for (int i=0;i<8;i++) t += red[i][f];
    ep[b*128+f] = t;
  }
}

// ---------------- tensor network scoring ----------------
__global__ __launch_bounds__(256) void k_tnet(const float* __restrict__ e1, const float* __restrict__ e2,
    const float* __restrict__ tn_w, const float* __restrict__ tn_wb, const float* __restrict__ tn_bias,
    float* __restrict__ tsout){
  int b = blockIdx.x; int t = threadIdx.x; int tt = t & 15; int fs = t >> 4;
  __shared__ float E1[128], E2[128], red[16][17];
  if (t < 128){ E1[t] = e1[b*128+t]; E2[t] = e2[b*128+t]; }
  __syncthreads();
  float acc = 0.f;
  for (int f = fs*8; f < fs*8+8; f++){
    const float* tw = tn_w + f*128*16 + tt;
    float partial = 0.f;
    for (int g=0; g<128; g++) partial += E2[g]*tw[g*16];
    acc += E1[f]*partial;
  }
  red[fs][tt] = acc;
  __syncthreads();
  if (t < 16){
    float s = 0.f;
    #pragma unroll
    for (int i=0;i<16;i++) s += red[i][t];
    float acc2 = 0.f;
    for (int c=0;c<128;c++) acc2 += tn_wb[t*256+c]*E1[c] + tn_wb[t*256+128+c]*E2[c];
    float v = s + acc2 + tn_bias[t];
    tsout[b*16+t] = v > 0.f ? v : 0.f;
  }
}

__global__ __launch_bounds__(128) void k_score2(const float* __restrict__ ts,
   const float* __restrict__ fc1_w, const float* __restrict__ fc1_b,
   const float* __restrict__ sc_w, const float* __restrict__ sc_b, float* __restrict__ out){
  int t = threadIdx.x; int b = t >> 4, i = t & 15;
  __shared__ float h2[8][17];
  float a = 0.f;
  #pragma unroll
  for (int k=0;k<16;k++) a += ts[b*16+k]*fc1_w[i*16+k];
  a += fc1_b[i];
  h2[b][i] = a > 0.f ? a : 0.f;
  __syncthreads();
  if (t < 8){
    float s = 0.f;
    #pragma unroll
    for (int k=0;k<16;k++) s += h2[t][k]*sc_w[k];
    s += sc_b[0];
    out[t] = 1.0f/(1.0f + expf(-s));
  }
}

extern "C" void kernel_launch(void* const* d_in, const int* in_sizes, int n_in,
                              void* d_out, int out_size, void* d_ws, size_t ws_size,
                              hipStream_t stream){
  const float* f1  = (const float*)d_in[0];
  const float* f2  = (const float*)d_in[1];
  const float* sw1 = (const float*)d_in[2];  const float* sg1 = (const float*)d_in[3];  const float* sb1 = (const float*)d_in[4];
  const float* fw1 = (const float*)d_in[5];  const float* fg1 = (const float*)d_in[6];  const float* fb1 = (const float*)d_in[7];
  const float* sw2 = (const float*)d_in[8];  const float* sg2 = (const float*)d_in[9];  const float* sb2 = (const float*)d_in[10];
  const float* fw2 = (const float*)d_in[11]; const float* fg2 = (const float*)d_in[12]; const float* fb2 = (const float*)d_in[13];
  const float* sw3 = (const float*)d_in[14]; const float* sg3 = (const float*)d_in[15]; const float* sb3 = (const float*)d_in[16];
  const float* fw3 = (const float*)d_in[17]; const float* fg3 = (const float*)d_in[18]; const float* fb3 = (const float*)d_in[19];
  const float* ew  = (const float*)d_in[20]; const float* eg  = (const float*)d_in[21]; const float* eb  = (const float*)d_in[22];
  const float* att_w   = (const float*)d_in[23];
  const float* tn_w    = (const float*)d_in[24];
  const float* tn_wb   = (const float*)d_in[25];
  const float* tn_bias = (const float*)d_in[26];
  const float* fc1_w   = (const float*)d_in[27];
  const float* fc1_b   = (const float*)d_in[28];
  const float* sc_w    = (const float*)d_in[29];
  const float* sc_b    = (const float*)d_in[30];

  float* W    = (float*)d_ws;
  float* T0   = W;                  // 2,097,152  (16384 x <=128)
  float* T1   = W + 2097152;        // 2,097,152
  float* X3S3 = W + 4194304;        // 4,194,304  (16384 x 256)
  float* EMB  = W + 8388608;        // 2,097,152  (16384 x 128)
  float* xx   = W + 10485760;       // 16384
  float* gcb  = W + 10504192;       // 2048
  float* scb  = W + 10506240;       // 16384
  float* ep   = W + 10522624;       // 2048
  float* tsb  = W + 10524672;       // 128
  int*   idxb = (int*)(W + 10524800);            // 327680 ints
  unsigned short* PH = (unsigned short*)(W + 10852480); // packed frags hi (1M floats)
  unsigned short* PL = (unsigned short*)(W + 11901056); // packed frags lo (1M floats)
  unsigned short* PWH = (unsigned short*)(W + 12949632); // packed weight hi (16K floats)
  unsigned short* PWL = (unsigned short*)(W + 12966016); // packed weight lo (16K floats)
  float* REG  = W + 12982400;       // Y (<= 4M floats)

  (void)ws_size;
  float* out = (float*)d_out;

  auto edge = [&](const float* xin, int C, int O,
                  const float* w, const float* g, const float* bb,
                  float* xout, int ldo, int ooff){
    int Kp = (C + 15) & ~15;
    int nkc = Kp >> 4;
    int npair = 2*O/64;
    int nwblk = ((2*O/32)*nkc*64 + 255)/256;
    int nymf  = 64*npair;
    k_pw<<<nwblk + 128*nkc, 256, 0, stream>>>(xin, PH, PL, xx, w, PWH, PWL, C, Kp, O, nwblk);
    k_dy<<<nymf + 512, 512, 0, stream>>>(PH, PL, PWH, PWL, xx, idxb, REG, Kp, 2*O, npair, nymf);
    k_edge<<<16384/(256/O), 256, 0, stream>>>(REG, idxb, g, bb, xout, O, ldo, ooff);
  };

  // xyz path (both point clouds as batches 0-7 / 8-15)
  k_extract<<<(8*3*1024+255)/256, 256, 0, stream>>>(f1, T0, 0, 3, 0);
  k_extract<<<(8*3*1024+255)/256, 256, 0, stream>>>(f2, T0, 0, 3, 8);
  edge(T0, 3,   64, sw1, sg1, sb1, T1, 64, 0);
  edge(T1, 64,  64, sw2, sg2, sb2, T0, 64, 0);
  edge(T0, 64, 128, sw3, sg3, sb3, X3S3, 256, 0);    // x3 -> cols 0..127
  // sem path
  k_extract<<<(8*128*1024+255)/256, 256, 0, stream>>>(f1, T0, 3, 128, 0);
  k_extract<<<(8*128*1024+255)/256, 256, 0, stream>>>(f2, T0, 3, 128, 8);
  edge(T0, 128, 64, fw1, fg1, fb1, T1, 64, 0);
  edge(T1, 64,  64, fw2, fg2, fb2, T0, 64, 0);
  edge(T0, 64, 128, fw3, fg3, fb3, X3S3, 256, 128);  // s3 -> cols 128..255
  // combine: emb = lrelu(eg * (X3S3 @ ew^T)/sqrt(1+eps) + eb)
  k_gthin<<<dim3(2, 512, 1), 256, 0, stream>>>(X3S3, ew, EMB, 256, 128,
        0, eg, eb, 1);
  // attention over all 16 batches
  k_meangc<<<16, 1024, 0, stream>>>(EMB, att_w, gcb);
  k_sc<<<16384, 64, 0, stream>>>(EMB, gcb, scb, out + 8);
  k_pool<<<16, 1024, 0, stream>>>(EMB, scb, ep);

  k_tnet<<<8, 256, 0, stream>>>(ep, ep + 1024, tn_w, tn_wb, tn_bias, tsb);
  k_score2<<<1, 128, 0, stream>>>(tsb, fc1_w, fc1_b, sc_w, sc_b, out);
}

// Round 9
// 491.664 us; speedup vs baseline: 1.1745x; 1.1745x over previous
//
#include <hip/hip_runtime.h>
#include <math.h>

#define INV_SQRT1P 0.99999500003749968754f   // 1/sqrt(1+1e-5)

typedef short v8s  __attribute__((ext_vector_type(8)));
typedef float v16f __attribute__((ext_vector_type(16)));

static __device__ __forceinline__ float lrelu(float f){ return f >= 0.0f ? f : 0.2f*f; }

// count of set bits in m strictly below this lane
static __device__ __forceinline__ int lanecnt_below(unsigned long long m){
  int c = __builtin_amdgcn_mbcnt_lo((unsigned)m, 0u);
  return __builtin_amdgcn_mbcnt_hi((unsigned)(m >> 32), c);
}

// ---------------- extract xyz (C=3) for BOTH inputs in one launch ----------------
__global__ void k_ext3(const float* __restrict__ f1, const float* __restrict__ f2,
                       float* __restrict__ out){
  int i = blockIdx.x*256 + threadIdx.x;
  int half = 8*3*1024;
  if (i >= 2*half) return;
  const float* f = (i < half) ? f1 : f2;
  int boff = (i < half) ? 0 : 8;
  int ii = (i < half) ? i : i - half;
  int n  = ii & 1023;
  int bc = ii >> 10;
  int c  = bc % 3;
  int b  = bc / 3;
  out[((size_t)(((b+boff)<<10)+n))*3 + c] = f[((size_t)(b*131 + c) << 10) + n];
}

// ---------------- extract sem (C=128) via LDS tile transpose, both inputs ----------
// tile: 32 channels x 64 positions; coalesced reads (256B rows) and writes (128B).
__global__ __launch_bounds__(256) void k_extT(const float* __restrict__ f1,
    const float* __restrict__ f2, float* __restrict__ out){
  __shared__ float T[32][65];
  int bid = blockIdx.x;              // 16 ntile x 4 ctile x 16 (input*8+b)
  int nt = bid & 15;
  int ct = (bid >> 4) & 3;
  int bb = bid >> 6;                 // 0..15
  const float* f = (bb < 8) ? f1 : f2;
  int b = bb & 7;
  int tid = threadIdx.x;
  #pragma unroll
  for (int it=0; it<8; it++){
    int cc = it*4 + (tid >> 6);      // 0..31
    int nn = tid & 63;
    T[cc][nn] = f[((size_t)(b*131 + 3 + ct*32 + cc) << 10) + nt*64 + nn];
  }
  __syncthreads();
  size_t rowb = ((size_t)bb << 10) + nt*64;
  #pragma unroll
  for (int it=0; it<8; it++){
    int nn = it*8 + (tid >> 5);      // 0..63
    int c  = tid & 31;
    out[(rowb + nn)*128 + ct*32 + c] = T[c][nn];
  }
}

// ---------------- fused pack: wpack blocks first, then X-pack blocks (with row xx) ----
__global__ __launch_bounds__(256) void k_pw(const float* __restrict__ X,
    unsigned short* __restrict__ PH, unsigned short* __restrict__ PL,
    float* __restrict__ xxout, const float* __restrict__ Wm,
    unsigned short* __restrict__ PWH, unsigned short* __restrict__ PWL,
    int C, int Kp, int O, int nwblk){
  int nkc = Kp >> 4;
  if ((int)blockIdx.x < nwblk){
    int gid = blockIdx.x*256 + threadIdx.x;
    int nchunk = (2*O/32)*nkc;
    if (gid >= nchunk*64) return;
    int lane = gid & 63;
    int chunk = gid >> 6;
    int jb = chunk / nkc, kc = chunk - jb*nkc;
    int j = jb*32 + (lane & 31);
    int k0 = kc*16 + ((lane>>5)<<3);
    unsigned short h[8], lo[8];
    #pragma unroll
    for (int t=0;t<8;t++){
      int k = k0 + t;
      float x = 0.f;
      if (k < C) x = (j < O) ? Wm[(size_t)j*2*C + k] : Wm[(size_t)(j-O)*2*C + C + k];
      unsigned u = __float_as_uint(x);
      unsigned h16 = (u + 0x7fffu + ((u>>16)&1u)) >> 16;
      float hf = __uint_as_float(h16 << 16);
      float lf = x - hf;
      unsigned ul = __float_as_uint(lf);
      unsigned l16 = (ul + 0x7fffu + ((ul>>16)&1u)) >> 16;
      h[t] = (unsigned short)h16; lo[t] = (unsigned short)l16;
    }
    size_t o = (size_t)chunk*512 + lane*8;
    *(v8s*)(PWH + o) = *(v8s*)h;
    *(v8s*)(PWL + o) = *(v8s*)lo;
  } else {
    int gid = (blockIdx.x - nwblk)*256 + threadIdx.x;   // grid exact: 512*nkc*64 threads
    int lane = gid & 63;
    int chunk = gid >> 6;
    int rb = chunk / nkc, kc = chunk - rb*nkc;
    int row = rb*32 + (lane & 31);
    int k0 = kc*16 + ((lane>>5)<<3);
    unsigned short h[8], lo[8];
    const float* Xr = X + (size_t)row*C;
    #pragma unroll
    for (int j=0;j<8;j++){
      int k = k0 + j;
      float x = (k < C) ? Xr[k] : 0.f;
      unsigned u = __float_as_uint(x);
      unsigned h16 = (u + 0x7fffu + ((u>>16)&1u)) >> 16;
      float hf = __uint_as_float(h16 << 16);
      float lf = x - hf;
      unsigned ul = __float_as_uint(lf);
      unsigned l16 = (ul + 0x7fffu + ((ul>>16)&1u)) >> 16;
      h[j] = (unsigned short)h16; lo[j] = (unsigned short)l16;
    }
    size_t o = (size_t)chunk*512 + lane*8;
    *(v8s*)(PH + o) = *(v8s*)h;
    *(v8s*)(PL + o) = *(v8s*)lo;
    if (kc == 0 && (lane & 32) == 0){
      float s = 0.f;
      for (int c=0;c<C;c++) s += Xr[c]*Xr[c];    // ascending order == old k_xx
      xxout[row] = s;
    }
  }
}

// ---------------- merged Y-GEMM + distance/top-20 (round-7 selection, + XCD swizzle) ----
__global__ __launch_bounds__(512) void k_dy(const unsigned short* __restrict__ PH,
    const unsigned short* __restrict__ PL, const unsigned short* __restrict__ PWH,
    const unsigned short* __restrict__ PWL, const float* __restrict__ xx,
    int* __restrict__ idx, float* __restrict__ Y, int Kp, int N, int npair, int nymf){
  __shared__ float Sl[16][1024];          // 64 KB
  int wave = threadIdx.x >> 6;
  int l = threadIdx.x & 63;
  int nkc = Kp >> 4;

  if ((int)blockIdx.x < nymf){
    // ---- ymf part: gw = blockIdx*8 + wave covers (mt, pair) ----
    int gw = blockIdx.x*8 + wave;
    int mt = gw / npair;
    int pair = gw - mt*npair;
    int jb0 = pair*2, jb1 = pair*2 + 1;
    size_t ao  = ((size_t)mt*nkc)*512 + l*8;
    size_t b0o = ((size_t)jb0*nkc)*512 + l*8;
    size_t b1o = ((size_t)jb1*nkc)*512 + l*8;
    v16f acc0, acc1;
    #pragma unroll
    for (int i=0;i<16;i++){ acc0[i] = 0.f; acc1[i] = 0.f; }
    for (int kc=0; kc<nkc; kc++){
      v8s Ah  = *(const v8s*)(PH + ao);
      v8s Al  = *(const v8s*)(PL + ao);
      v8s B0h = *(const v8s*)(PWH + b0o);
      v8s B0l = *(const v8s*)(PWL + b0o);
      v8s B1h = *(const v8s*)(PWH + b1o);
      v8s B1l = *(const v8s*)(PWL + b1o);
      acc0 = __builtin_amdgcn_mfma_f32_32x32x16_bf16(Ah, B0h, acc0, 0, 0, 0);
      acc1 = __builtin_amdgcn_mfma_f32_32x32x16_bf16(Ah, B1h, acc1, 0, 0, 0);
      acc0 = __builtin_amdgcn_mfma_f32_32x32x16_bf16(Ah, B0l, acc0, 0, 0, 0);
      acc1 = __builtin_amdgcn_mfma_f32_32x32x16_bf16(Ah, B1l, acc1, 0, 0, 0);
      acc0 = __builtin_amdgcn_mfma_f32_32x32x16_bf16(Al, B0h, acc0, 0, 0, 0);
      acc1 = __builtin_amdgcn_mfma_f32_32x32x16_bf16(Al, B1h, acc1, 0, 0, 0);
      ao += 512; b0o += 512; b1o += 512;
    }
    int rbase = mt*32;
    int c0 = pair*64 + (l & 31), c1 = c0 + 32;
    #pragma unroll
    for (int r=0;r<16;r++){
      int rl_ = (r&3) + ((r>>2)<<3) + ((l>>5)<<2);
      float* dst = Y + (size_t)(rbase + rl_)*N;
      dst[c0] = acc0[r];
      dst[c1] = acc1[r];
    }
    return;
  }

  // ---- dtk part: XCD swizzle (nymf multiple of 8; XCD k gets rowblocks [64k,64k+64)) ----
  int t = blockIdx.x - nymf;              // 0..511
  int rb = ((t & 7) << 6) | (t >> 3);
  int batch = rb >> 5;
  const float* xxb = xx + (batch<<10);
  int rbase_local = (rb & 31)*32;

  v16f acc[4];
  #pragma unroll
  for (int i=0;i<4;i++){
    #pragma unroll
    for (int j=0;j<16;j++) acc[i][j] = 0.f;
  }
  #pragma unroll
  for (int pp=0; pp<2; pp++){
    int pair = wave*2 + pp;
    size_t a   = ((size_t)rb*nkc)*512 + l*8;
    size_t b0o = ((size_t)(batch*32 + 2*pair)*nkc)*512 + l*8;
    size_t b1o = b0o + (size_t)nkc*512;
    for (int kc=0; kc<nkc; kc++){
      v8s Ah  = *(const v8s*)(PH + a);
      v8s Al  = *(const v8s*)(PL + a);
      v8s B0h = *(const v8s*)(PH + b0o);
      v8s B0l = *(const v8s*)(PL + b0o);
      v8s B1h = *(const v8s*)(PH + b1o);
      v8s B1l = *(const v8s*)(PL + b1o);
      acc[2*pp]   = __builtin_amdgcn_mfma_f32_32x32x16_bf16(Ah, B0h, acc[2*pp],   0, 0, 0);
      acc[2*pp+1] = __builtin_amdgcn_mfma_f32_32x32x16_bf16(Ah, B1h, acc[2*pp+1], 0, 0, 0);
      acc[2*pp]   = __builtin_amdgcn_mfma_f32_32x32x16_bf16(Ah, B0l, acc[2*pp],   0, 0, 0);
      acc[2*pp+1] = __builtin_amdgcn_mfma_f32_32x32x16_bf16(Ah, B1l, acc[2*pp+1], 0, 0, 0);
      acc[2*pp]   = __builtin_amdgcn_mfma_f32_32x32x16_bf16(Al, B0h, acc[2*pp],   0, 0, 0);
      acc[2*pp+1] = __builtin_amdgcn_mfma_f32_32x32x16_bf16(Al, B1h, acc[2*pp+1], 0, 0, 0);
      a += 512; b0o += 512; b1o += 512;
    }
  }

  #pragma unroll
  for (int h=0; h<2; h++){
    // ---- write rows [16h,16h+16) of the tile into LDS with neg_d epilogue ----
    #pragma unroll
    for (int pp=0; pp<2; pp++){
      int pair = wave*2 + pp;
      int c0 = pair*64 + (l & 31), c1 = c0 + 32;
      float xc0 = xxb[c0], xc1 = xxb[c1];
      #pragma unroll
      for (int r = 0; r < 8; r++){
        int rr = h*8 + r;
        int rl = (rr&3) + (((rr>>2)&1)<<3) + ((l>>5)<<2);  // 0..15
        float xr = xxb[rbase_local + h*16 + rl];
        Sl[rl][c0] = 2.f*acc[2*pp][rr]   - xr - xc0;
        Sl[rl][c1] = 2.f*acc[2*pp+1][rr] - xr - xc1;
      }
    }
    __syncthreads();
    // ---- exact top-20: 2 rows per wave, processed in parallel by half-waves ----
    {
      int hi = l >> 5;
      int li = l & 31;
      int rloc = wave*2 + hi;
      int grow = rb*32 + h*16 + rloc;
      int out_base = grow*20;
      unsigned long long hm = hi ? 0xFFFFFFFF00000000ull : 0x00000000FFFFFFFFull;

      // 32 values per lane; index m = li + 32*j (slot order == ascending index)
      unsigned kv[32];
      #pragma unroll
      for (int j=0;j<32;j++){
        unsigned u = __float_as_uint(Sl[rloc][li + 32*j]);
        kv[j] = (u & 0x80000000u) ? ~u : (u | 0x80000000u);
      }

      unsigned lmax = kv[0];
      #pragma unroll
      for (int j=1;j<32;j++) lmax = lmax > kv[j] ? lmax : kv[j];

      // tau = 20th-largest lane-max within this half (prefilter, >=20 survivors)
      unsigned tau = 0u;
      #pragma unroll
      for (int bit=31; bit>=0; --bit){
        unsigned cand = tau | (1u << bit);
        unsigned long long M = __ballot(lmax >= cand);
        int c = hi ? __popc((unsigned)(M >> 32)) : __popc((unsigned)M);
        tau = (c >= 20) ? cand : tau;        // per-lane cndmask, no branch
      }

      // compact survivors (value<<32 | index) into this row's scratch
      unsigned long long* sl = (unsigned long long*)&Sl[rloc][0];
      sl[li] = 0ull; sl[li+32] = 0ull;
      int b2 = 0;
      #pragma unroll
      for (int j=0;j<32;j++){
        bool p = kv[j] >= tau;
        unsigned long long M = __ballot(p) & hm;
        if (p){
          int s = b2 + lanecnt_below(M);
          if (s < 64) sl[s] = ((unsigned long long)kv[j] << 32) | (unsigned)(li + 32*j);
        }
        b2 += __popcll(M);
      }

      if (b2 <= 64){
        unsigned long long pk0 = sl[li], pk1 = sl[li+32];  // empty slots: key 0
        // exact 20th-largest among survivors
        unsigned vcur = 0u;
        #pragma unroll
        for (int bit=31; bit>=0; --bit){
          unsigned long long cc = (unsigned long long)(vcur | (1u << bit)) << 32;
          unsigned long long B0 = __ballot(pk0 >= cc);
          unsigned long long B1 = __ballot(pk1 >= cc);
          int clo = __popc((unsigned)B0) + __popc((unsigned)B1);
          int chi = __popc((unsigned)(B0>>32)) + __popc((unsigned)(B1>>32));
          int c = hi ? chi : clo;
          vcur = (c >= 20) ? (vcur | (1u << bit)) : vcur;
        }
        unsigned k0 = (unsigned)(pk0 >> 32), k1 = (unsigned)(pk1 >> 32);
        unsigned long long G0 = __ballot(k0 > vcur) & hm;
        unsigned long long G1 = __ballot(k1 > vcur) & hm;
        int ng0 = __popcll(G0);
        int c1  = ng0 + __popcll(G1);
        if (k0 > vcur) idx[out_base + lanecnt_below(G0)] = (int)(pk0 & 0xffffffffu);
        if (k1 > vcur) idx[out_base + ng0 + lanecnt_below(G1)] = (int)(pk1 & 0xffffffffu);
        unsigned long long E0 = __ballot(k0 == vcur) & hm;
        unsigned long long E1 = __ballot(k1 == vcur) & hm;
        int ne0 = __popcll(E0);
        if (k0 == vcur){ int s = c1 + lanecnt_below(E0); if (s < 20) idx[out_base + s] = (int)(pk0 & 0xffffffffu); }
        if (k1 == vcur){ int s = c1 + ne0 + lanecnt_below(E1); if (s < 20) idx[out_base + s] = (int)(pk1 & 0xffffffffu); }
      } else {
        // rare (near-degenerate ties): exact search over all 1024 values
        unsigned cur = 0u;
        #pragma unroll 1
        for (int bit=31; bit>=0; --bit){
          unsigned cand = cur | (1u << bit);
          int lc = 0;
          #pragma unroll
          for (int j=0;j<32;j++) lc += (kv[j] >= cand) ? 1 : 0;
          #pragma unroll
          for (int off=1; off<32; off<<=1) lc += __shfl_xor(lc, off, 64);  // within-half sum
          cur = (lc >= 20) ? cand : cur;
        }
        int bse = 0;
        #pragma unroll 1
        for (int j=0;j<32;j++){
          unsigned long long Mg = __ballot(kv[j] > cur) & hm;
          if (kv[j] > cur){ int s = bse + lanecnt_below(Mg); idx[out_base + s] = li + 32*j; }
          bse += __popcll(Mg);
        }
        #pragma unroll 1
        for (int j=0;j<32;j++){
          unsigned long long Me = __ballot(kv[j] == cur) & hm;
          if (kv[j] == cur){ int s = bse + lanecnt_below(Me); if (s < 20) idx[out_base + s] = li + 32*j; }
          bse += __popcll(Me);
          if (bse >= 20) break;
        }
      }
    }
    __syncthreads();
  }
}

// ---------------- thin NT GEMM (kept for the emb combine) ----------------
__global__ __launch_bounds__(256) void k_gthin(
    const float* __restrict__ Am, const float* __restrict__ Bm, float* __restrict__ Om,
    int K, int ldo, int wmode, const float* __restrict__ p1, const float* __restrict__ p2, int ep)
{
  __shared__ float As[64][33];
  __shared__ float Bs[64][68];
  int tid = threadIdx.x;
  int tx = tid & 15, ty = tid >> 4;
  int rbase = blockIdx.y*32, cbase = blockIdx.x*64;
  float acc[2][4];
  #pragma unroll
  for (int i=0;i<2;i++){ acc[i][0]=0.f; acc[i][1]=0.f; acc[i][2]=0.f; acc[i][3]=0.f; }

  for (int c0=0; c0<K; c0+=64){
    int cw = K - c0; if (cw > 64) cw = 64;
    #pragma unroll
    for (int p=0; p<2; p++){
      int idx = p*256 + tid;
      int kq = idx & 15, row = idx >> 4;
      const float* src = Am + (size_t)(rbase+row)*K + c0 + kq*4;
      float4 v = {0.f,0.f,0.f,0.f};
      if (kq*4 + 4 <= cw) v = *(const float4*)src;
      else {
        if (kq*4+0 < cw) v.x = src[0];
        if (kq*4+1 < cw) v.y = src[1];
        if (kq*4+2 < cw) v.z = src[2];
        if (kq*4+3 < cw) v.w = src[3];
      }
      As[kq*4+0][row]=v.x; As[kq*4+1][row]=v.y; As[kq*4+2][row]=v.z; As[kq*4+3][row]=v.w;
    }
    #pragma unroll
    for (int p=0; p<4; p++){
      int idx = p*256 + tid;
      int kq = idx & 15, col = idx >> 4;
      int j = cbase + col;
      const float* src = (wmode > 0)
          ? ((j < wmode) ? Bm + (size_t)j*2*K + c0 + kq*4
                         : Bm + (size_t)(j-wmode)*2*K + K + c0 + kq*4)
          : Bm + (size_t)j*K + c0 + kq*4;
      float4 v = {0.f,0.f,0.f,0.f};
      if (kq*4 + 4 <= cw) v = *(const float4*)src;
      else {
        if (kq*4+0 < cw) v.x = src[0];
        if (kq*4+1 < cw) v.y = src[1];
        if (kq*4+2 < cw) v.z = src[2];
        if (kq*4+3 < cw) v.w = src[3];
      }
      int swb = (kq & 14) << 1;
      int cs = col ^ swb;
      Bs[kq*4+0][cs]=v.x; Bs[kq*4+1][cs]=v.y; Bs[kq*4+2][cs]=v.z; Bs[kq*4+3][cs]=v.w;
    }
    __syncthreads();
    for (int k=0;k<cw;k++){
      int sw = ((k>>3)&7)<<2;
      float a0 = As[k][ty*2], a1 = As[k][ty*2+1];
      float b[4];
      *(float4*)b = *(const float4*)&Bs[k][(tx*4) ^ sw];
      acc[0][0]+=a0*b[0]; acc[0][1]+=a0*b[1]; acc[0][2]+=a0*b[2]; acc[0][3]+=a0*b[3];
      acc[1][0]+=a1*b[0]; acc[1][1]+=a1*b[1]; acc[1][2]+=a1*b[2]; acc[1][3]+=a1*b[3];
    }
    __syncthreads();
  }
  #pragma unroll
  for (int i=0;i<2;i++){
    int r = rbase + ty*2 + i;
    float o[4];
    #pragma unroll
    for (int j=0;j<4;j++){
      int cc = cbase + tx*4 + j;
      float v = acc[i][j];
      if (ep == 1) v = lrelu(p1[cc]*v*INV_SQRT1P + p2[cc]);
      o[j] = v;
    }
    *(float4*)(Om + (size_t)r*ldo + cbase + tx*4) = *(float4*)o;
  }
}

// ---------------- edge epilogue, multi-row blocks (256 threads) ----------------
__global__ __launch_bounds__(256) void k_edge(const float* __restrict__ Y, const int* __restrict__ idx,
    const float* __restrict__ g, const float* __restrict__ bias,
    float* __restrict__ out, int O, int ldo, int ooff){
  int rpb = 256/O;
  int rloc = threadIdx.x/O;
  int o = threadIdx.x - rloc*O;
  int row = blockIdx.x*rpb + rloc;
  int b = row >> 10;
  __shared__ int js[4][20];
  int nj = rpb*20;
  if (threadIdx.x < nj) js[threadIdx.x/20][threadIdx.x%20] = idx[(blockIdx.x*rpb)*20 + threadIdx.x];
  __syncthreads();
  int O2 = O*2;
  float y1c = Y[(size_t)row*O2 + o];
  float d   = Y[(size_t)row*O2 + O + o] - y1c;
  float sc  = g[o] * INV_SQRT1P;
  float bb  = bias[o];
  const float* Yb = Y + ((size_t)(b<<10))*O2;
  float best = -1e38f;
  #pragma unroll
  for (int k=0;k<20;k++){
    float f = sc * (Yb[(size_t)js[rloc][k]*O2 + o] + d) + bb;
    best = fmaxf(best, lrelu(f));
  }
  out[(size_t)row*ldo + ooff + o] = best;
}

// ---------------- attention (16 batches): fused mean + gc ----------------
__global__ __launch_bounds__(1024) void k_meangc(const float* __restrict__ emb,
     const float* __restrict__ att_w, float* __restrict__ gc){
  int b = blockIdx.x; int f = threadIdx.x & 127; int ny = threadIdx.x >> 7;
  const float* e = emb + ((size_t)(b<<10) + ny*128)*128 + f;
  float s = 0.f;
  for (int n=0;n<128;n++) s += e[n*128];
  __shared__ float red[8][128];
  __shared__ float mr[128];
  red[ny][f] = s;
  __syncthreads();
  if (ny == 0){
    float t = 0.f;
    #pragma unroll
    for (int i=0;i<8;i++) t += red[i][f];
    mr[f] = t * (1.0f/1024.0f);
  }
  __syncthreads();
  if (threadIdx.x < 128){
    int g = threadIdx.x;
    float s2 = 0.f;
    for (int ff=0; ff<128; ff++) s2 += mr[ff]*att_w[ff*128+g];
    gc[b*128+g] = tanhf(s2);
  }
}

// ---------------- sc: 4 rows per block (4 waves), same per-wave math ----------------
__global__ __launch_bounds__(256) void k_sc(const float* __restrict__ emb, const float* __restrict__ gc,
     float* __restrict__ sc, float* __restrict__ attout){
  int wave = threadIdx.x >> 6;
  int l = threadIdx.x & 63;
  int row = blockIdx.x*4 + wave;
  int b = row >> 10;
  const float* e  = emb + (size_t)row*128;
  const float* gb = gc + b*128;
  float p = e[l]*gb[l] + e[l+64]*gb[l+64];
  #pragma unroll
  for (int off=32; off>0; off>>=1) p += __shfl_xor(p, off, 64);
  if (l == 0){
    float s = 1.0f/(1.0f + expf(-p));
    sc[row] = s;
    attout[row] = s;
  }
}

__global__ __launch_bounds__(1024) void k_pool(const float* __restrict__ emb, const float* __restrict__ sc,
     float* __restrict__ ep){
  int b = blockIdx.x; int f = threadIdx.x & 127; int ny = threadIdx.x >> 7;
  const float* e  = emb + ((size_t)(b<<10) + ny*128)*128 + f;
  const float* sb = sc + (b<<10) + ny*128;
  float s = 0.f;
  for (int n=0;n<128;n++) s += e[n*128]*sb[n];
  __shared__ float red[8][128];
  red[ny][f] = s;
  __syncthreads();
  if (ny == 0){
    float t = 0.f;
    #pragma unroll
    for (int i=0;i<8;i++) t += red[i][f];
    ep[b*128+f] = t;
  }
}

// ---------------- tensor network scoring ----------------
__global__ __launch_bounds__(256) void k_tnet(const float* __restrict__ e1, const float* __restrict__ e2,
    const float* __restrict__ tn_w, const float* __restrict__ tn_wb, const float* __restrict__ tn_bias,
    float* __restrict__ tsout){
  int b = blockIdx.x; int t = threadIdx.x; int tt = t & 15; int fs = t >> 4;
  __shared__ float E1[128], E2[128], red[16][17];
  if (t < 128){ E1[t] = e1[b*128+t]; E2[t] = e2[b*128+t]; }
  __syncthreads();
  float acc = 0.f;
  for (int f = fs*8; f < fs*8+8; f++){
    const float* tw = tn_w + f*128*16 + tt;
    float partial = 0.f;
    for (int g=0; g<128; g++) partial += E2[g]*tw[g*16];
    acc += E1[f]*partial;
  }
  red[fs][tt] = acc;
  __syncthreads();
  if (t < 16){
    float s = 0.f;
    #pragma unroll
    for (int i=0;i<16;i++) s += red[i][t];
    float acc2 = 0.f;
    for (int c=0;c<128;c++) acc2 += tn_wb[t*256+c]*E1[c] + tn_wb[t*256+128+c]*E2[c];
    float v = s + acc2 + tn_bias[t];
    tsout[b*16+t] = v > 0.f ? v : 0.f;
  }
}

__global__ __launch_bounds__(128) void k_score2(const float* __restrict__ ts,
   const float* __restrict__ fc1_w, const float* __restrict__ fc1_b,
   const float* __restrict__ sc_w, const float* __restrict__ sc_b, float* __restrict__ out){
  int t = threadIdx.x; int b = t >> 4, i = t & 15;
  __shared__ float h2[8][17];
  float a = 0.f;
  #pragma unroll
  for (int k=0;k<16;k++) a += ts[b*16+k]*fc1_w[i*16+k];
  a += fc1_b[i];
  h2[b][i] = a > 0.f ? a : 0.f;
  __syncthreads();
  if (t < 8){
    float s = 0.f;
    #pragma unroll
    for (int k=0;k<16;k++) s += h2[t][k]*sc_w[k];
    s += sc_b[0];
    out[t] = 1.0f/(1.0f + expf(-s));
  }
}

extern "C" void kernel_launch(void* const* d_in, const int* in_sizes, int n_in,
                              void* d_out, int out_size, void* d_ws, size_t ws_size,
                              hipStream_t stream){
  const float* f1  = (const float*)d_in[0];
  const float* f2  = (const float*)d_in[1];
  const float* sw1 = (const float*)d_in[2];  const float* sg1 = (const float*)d_in[3];  const float* sb1 = (const float*)d_in[4];
  const float* fw1 = (const float*)d_in[5];  const float* fg1 = (const float*)d_in[6];  const float* fb1 = (const float*)d_in[7];
  const float* sw2 = (const float*)d_in[8];  const float* sg2 = (const float*)d_in[9];  const float* sb2 = (const float*)d_in[10];
  const float* fw2 = (const float*)d_in[11]; const float* fg2 = (const float*)d_in[12]; const float* fb2 = (const float*)d_in[13];
  const float* sw3 = (const float*)d_in[14]; const float* sg3 = (const float*)d_in[15]; const float* sb3 = (const float*)d_in[16];
  const float* fw3 = (const float*)d_in[17]; const float* fg3 = (const float*)d_in[18]; const float* fb3 = (const float*)d_in[19];
  const float* ew  = (const float*)d_in[20]; const float* eg  = (const float*)d_in[21]; const float* eb  = (const float*)d_in[22];
  const float* att_w   = (const float*)d_in[23];
  const float* tn_w    = (const float*)d_in[24];
  const float* tn_wb   = (const float*)d_in[25];
  const float* tn_bias = (const float*)d_in[26];
  const float* fc1_w   = (const float*)d_in[27];
  const float* fc1_b   = (const float*)d_in[28];
  const float* sc_w    = (const float*)d_in[29];
  const float* sc_b    = (const float*)d_in[30];

  float* W    = (float*)d_ws;
  float* T0   = W;                  // 2,097,152  (16384 x <=128)
  float* T1   = W + 2097152;        // 2,097,152
  float* X3S3 = W + 4194304;        // 4,194,304  (16384 x 256)
  float* EMB  = W + 8388608;        // 2,097,152  (16384 x 128)
  float* xx   = W + 10485760;       // 16384
  float* gcb  = W + 10504192;       // 2048
  float* scb  = W + 10506240;       // 16384
  float* ep   = W + 10522624;       // 2048
  float* tsb  = W + 10524672;       // 128
  int*   idxb = (int*)(W + 10524800);            // 327680 ints
  unsigned short* PH = (unsigned short*)(W + 10852480); // packed frags hi (1M floats)
  unsigned short* PL = (unsigned short*)(W + 11901056); // packed frags lo (1M floats)
  unsigned short* PWH = (unsigned short*)(W + 12949632); // packed weight hi (16K floats)
  unsigned short* PWL = (unsigned short*)(W + 12966016); // packed weight lo (16K floats)
  float* REG  = W + 12982400;       // Y (<= 4M floats)

  (void)ws_size;
  float* out = (float*)d_out;

  auto edge = [&](const float* xin, int C, int O,
                  const float* w, const float* g, const float* bb,
                  float* xout, int ldo, int ooff){
    int Kp = (C + 15) & ~15;
    int nkc = Kp >> 4;
    int npair = 2*O/64;
    int nwblk = ((2*O/32)*nkc*64 + 255)/256;
    int nymf  = 64*npair;
    k_pw<<<nwblk + 128*nkc, 256, 0, stream>>>(xin, PH, PL, xx, w, PWH, PWL, C, Kp, O, nwblk);
    k_dy<<<nymf + 512, 512, 0, stream>>>(PH, PL, PWH, PWL, xx, idxb, REG, Kp, 2*O, npair, nymf);
    k_edge<<<16384/(256/O), 256, 0, stream>>>(REG, idxb, g, bb, xout, O, ldo, ooff);
  };

  // xyz path (both point clouds as batches 0-7 / 8-15), one launch
  k_ext3<<<(2*8*3*1024+255)/256, 256, 0, stream>>>(f1, f2, T0);
  edge(T0, 3,   64, sw1, sg1, sb1, T1, 64, 0);
  edge(T1, 64,  64, sw2, sg2, sb2, T0, 64, 0);
  edge(T0, 64, 128, sw3, sg3, sb3, X3S3, 256, 0);    // x3 -> cols 0..127
  // sem path: LDS-transpose extract, both inputs, one launch
  k_extT<<<1024, 256, 0, stream>>>(f1, f2, T0);
  edge(T0, 128, 64, fw1, fg1, fb1, T1, 64, 0);
  edge(T1, 64,  64, fw2, fg2, fb2, T0, 64, 0);
  edge(T0, 64, 128, fw3, fg3, fb3, X3S3, 256, 128);  // s3 -> cols 128..255
  // combine: emb = lrelu(eg * (X3S3 @ ew^T)/sqrt(1+eps) + eb)
  k_gthin<<<dim3(2, 512, 1), 256, 0, stream>>>(X3S3, ew, EMB, 256, 128,
        0, eg, eb, 1);
  // attention over all 16 batches
  k_meangc<<<16, 1024, 0, stream>>>(EMB, att_w, gcb);
  k_sc<<<4096, 256, 0, stream>>>(EMB, gcb, scb, out + 8);
  k_pool<<<16, 1024, 0, stream>>>(EMB, scb, ep);

  k_tnet<<<8, 256, 0, stream>>>(ep, ep + 1024, tn_w, tn_wb, tn_bias, tsb);
  k_score2<<<1, 128, 0, stream>>>(tsb, fc1_w, fc1_b, sc_w, sc_b, out);
}

// Round 10
// 489.118 us; speedup vs baseline: 1.1806x; 1.0052x over previous
//
#include <hip/hip_runtime.h>
#include <math.h>

#define INV_SQRT1P 0.99999500003749968754f   // 1/sqrt(1+1e-5)

typedef short v8s  __attribute__((ext_vector_type(8)));
typedef float v16f __attribute__((ext_vector_type(16)));

static __device__ __forceinline__ float lrelu(float f){ return f >= 0.0f ? f : 0.2f*f; }

// count of set bits in m strictly below this lane
static __device__ __forceinline__ int lanecnt_below(unsigned long long m){
  int c = __builtin_amdgcn_mbcnt_lo((unsigned)m, 0u);
  return __builtin_amdgcn_mbcnt_hi((unsigned)(m >> 32), c);
}

// ---------------- extract xyz (C=3) for BOTH inputs in one launch ----------------
__global__ void k_ext3(const float* __restrict__ f1, const float* __restrict__ f2,
                       float* __restrict__ out){
  int i = blockIdx.x*256 + threadIdx.x;
  int half = 8*3*1024;
  if (i >= 2*half) return;
  const float* f = (i < half) ? f1 : f2;
  int boff = (i < half) ? 0 : 8;
  int ii = (i < half) ? i : i - half;
  int n  = ii & 1023;
  int bc = ii >> 10;
  int c  = bc % 3;
  int b  = bc / 3;
  out[((size_t)(((b+boff)<<10)+n))*3 + c] = f[((size_t)(b*131 + c) << 10) + n];
}

// ---------------- extract sem (C=128) via LDS tile transpose, both inputs ----------
__global__ __launch_bounds__(256) void k_extT(const float* __restrict__ f1,
    const float* __restrict__ f2, float* __restrict__ out){
  __shared__ float T[32][65];
  int bid = blockIdx.x;              // 16 ntile x 4 ctile x 16 (input*8+b)
  int nt = bid & 15;
  int ct = (bid >> 4) & 3;
  int bb = bid >> 6;                 // 0..15
  const float* f = (bb < 8) ? f1 : f2;
  int b = bb & 7;
  int tid = threadIdx.x;
  #pragma unroll
  for (int it=0; it<8; it++){
    int cc = it*4 + (tid >> 6);      // 0..31
    int nn = tid & 63;
    T[cc][nn] = f[((size_t)(b*131 + 3 + ct*32 + cc) << 10) + nt*64 + nn];
  }
  __syncthreads();
  size_t rowb = ((size_t)bb << 10) + nt*64;
  #pragma unroll
  for (int it=0; it<8; it++){
    int nn = it*8 + (tid >> 5);      // 0..63
    int c  = tid & 31;
    out[(rowb + nn)*128 + ct*32 + c] = T[c][nn];
  }
}

// ---------------- fused pack: wpack blocks first, then X-pack blocks ----------------
// wsplit=1: Wm is (O, 2C) concat layout (B rows = 2O). wsplit=0: Wm is (nrowsB, C).
// doxx=1: kc==0/lane<32 thread computes xx[row] (ascending-c, bit-identical to k_xx).
__global__ __launch_bounds__(256) void k_pw(const float* __restrict__ X,
    unsigned short* __restrict__ PH, unsigned short* __restrict__ PL,
    float* __restrict__ xxout, const float* __restrict__ Wm,
    unsigned short* __restrict__ PWH, unsigned short* __restrict__ PWL,
    int C, int Kp, int O, int nwblk, int nrowsB, int wsplit, int doxx){
  int nkc = Kp >> 4;
  if ((int)blockIdx.x < nwblk){
    int gid = blockIdx.x*256 + threadIdx.x;
    int nchunk = (nrowsB/32)*nkc;
    if (gid >= nchunk*64) return;
    int lane = gid & 63;
    int chunk = gid >> 6;
    int jb = chunk / nkc, kc = chunk - jb*nkc;
    int j = jb*32 + (lane & 31);
    int k0 = kc*16 + ((lane>>5)<<3);
    unsigned short h[8], lo[8];
    #pragma unroll
    for (int t=0;t<8;t++){
      int k = k0 + t;
      float x = 0.f;
      if (k < C){
        if (wsplit) x = (j < O) ? Wm[(size_t)j*2*C + k] : Wm[(size_t)(j-O)*2*C + C + k];
        else        x = Wm[(size_t)j*C + k];
      }
      unsigned u = __float_as_uint(x);
      unsigned h16 = (u + 0x7fffu + ((u>>16)&1u)) >> 16;
      float hf = __uint_as_float(h16 << 16);
      float lf = x - hf;
      unsigned ul = __float_as_uint(lf);
      unsigned l16 = (ul + 0x7fffu + ((ul>>16)&1u)) >> 16;
      h[t] = (unsigned short)h16; lo[t] = (unsigned short)l16;
    }
    size_t o = (size_t)chunk*512 + lane*8;
    *(v8s*)(PWH + o) = *(v8s*)h;
    *(v8s*)(PWL + o) = *(v8s*)lo;
  } else {
    int gid = (blockIdx.x - nwblk)*256 + threadIdx.x;   // grid exact: 512*nkc*64 threads
    int lane = gid & 63;
    int chunk = gid >> 6;
    int rb = chunk / nkc, kc = chunk - rb*nkc;
    int row = rb*32 + (lane & 31);
    int k0 = kc*16 + ((lane>>5)<<3);
    unsigned short h[8], lo[8];
    const float* Xr = X + (size_t)row*C;
    #pragma unroll
    for (int j=0;j<8;j++){
      int k = k0 + j;
      float x = (k < C) ? Xr[k] : 0.f;
      unsigned u = __float_as_uint(x);
      unsigned h16 = (u + 0x7fffu + ((u>>16)&1u)) >> 16;
      float hf = __uint_as_float(h16 << 16);
      float lf = x - hf;
      unsigned ul = __float_as_uint(lf);
      unsigned l16 = (ul + 0x7fffu + ((ul>>16)&1u)) >> 16;
      h[j] = (unsigned short)h16; lo[j] = (unsigned short)l16;
    }
    size_t o = (size_t)chunk*512 + lane*8;
    *(v8s*)(PH + o) = *(v8s*)h;
    *(v8s*)(PL + o) = *(v8s*)lo;
    if (doxx && kc == 0 && (lane & 32) == 0){
      float s = 0.f;
      for (int c=0;c<C;c++) s += Xr[c]*Xr[c];    // ascending order == old k_xx
      xxout[row] = s;
    }
  }
}

// ---------------- merged Y-GEMM + distance/top-20 (round-7 selection + XCD swizzle) ----
__global__ __launch_bounds__(512) void k_dy(const unsigned short* __restrict__ PH,
    const unsigned short* __restrict__ PL, const unsigned short* __restrict__ PWH,
    const unsigned short* __restrict__ PWL, const float* __restrict__ xx,
    int* __restrict__ idx, float* __restrict__ Y, int Kp, int N, int npair, int nymf){
  __shared__ float Sl[16][1024];          // 64 KB
  int wave = threadIdx.x >> 6;
  int l = threadIdx.x & 63;
  int nkc = Kp >> 4;

  if ((int)blockIdx.x < nymf){
    // ---- ymf part: gw = blockIdx*8 + wave covers (mt, pair) ----
    int gw = blockIdx.x*8 + wave;
    int mt = gw / npair;
    int pair = gw - mt*npair;
    int jb0 = pair*2, jb1 = pair*2 + 1;
    size_t ao  = ((size_t)mt*nkc)*512 + l*8;
    size_t b0o = ((size_t)jb0*nkc)*512 + l*8;
    size_t b1o = ((size_t)jb1*nkc)*512 + l*8;
    v16f acc0, acc1;
    #pragma unroll
    for (int i=0;i<16;i++){ acc0[i] = 0.f; acc1[i] = 0.f; }
    for (int kc=0; kc<nkc; kc++){
      v8s Ah  = *(const v8s*)(PH + ao);
      v8s Al  = *(const v8s*)(PL + ao);
      v8s B0h = *(const v8s*)(PWH + b0o);
      v8s B0l = *(const v8s*)(PWL + b0o);
      v8s B1h = *(const v8s*)(PWH + b1o);
      v8s B1l = *(const v8s*)(PWL + b1o);
      acc0 = __builtin_amdgcn_mfma_f32_32x32x16_bf16(Ah, B0h, acc0, 0, 0, 0);
      acc1 = __builtin_amdgcn_mfma_f32_32x32x16_bf16(Ah, B1h, acc1, 0, 0, 0);
      acc0 = __builtin_amdgcn_mfma_f32_32x32x16_bf16(Ah, B0l, acc0, 0, 0, 0);
      acc1 = __builtin_amdgcn_mfma_f32_32x32x16_bf16(Ah, B1l, acc1, 0, 0, 0);
      acc0 = __builtin_amdgcn_mfma_f32_32x32x16_bf16(Al, B0h, acc0, 0, 0, 0);
      acc1 = __builtin_amdgcn_mfma_f32_32x32x16_bf16(Al, B1h, acc1, 0, 0, 0);
      ao += 512; b0o += 512; b1o += 512;
    }
    int rbase = mt*32;
    int c0 = pair*64 + (l & 31), c1 = c0 + 32;
    #pragma unroll
    for (int r=0;r<16;r++){
      int rl_ = (r&3) + ((r>>2)<<3) + ((l>>5)<<2);
      float* dst = Y + (size_t)(rbase + rl_)*N;
      dst[c0] = acc0[r];
      dst[c1] = acc1[r];
    }
    return;
  }

  // ---- dtk part: XCD swizzle (nymf multiple of 8; XCD k gets rowblocks [64k,64k+64)) ----
  int t = blockIdx.x - nymf;              // 0..511
  int rb = ((t & 7) << 6) | (t >> 3);
  int batch = rb >> 5;
  const float* xxb = xx + (batch<<10);
  int rbase_local = (rb & 31)*32;

  v16f acc[4];
  #pragma unroll
  for (int i=0;i<4;i++){
    #pragma unroll
    for (int j=0;j<16;j++) acc[i][j] = 0.f;
  }
  #pragma unroll
  for (int pp=0; pp<2; pp++){
    int pair = wave*2 + pp;
    size_t a   = ((size_t)rb*nkc)*512 + l*8;
    size_t b0o = ((size_t)(batch*32 + 2*pair)*nkc)*512 + l*8;
    size_t b1o = b0o + (size_t)nkc*512;
    for (int kc=0; kc<nkc; kc++){
      v8s Ah  = *(const v8s*)(PH + a);
      v8s Al  = *(const v8s*)(PL + a);
      v8s B0h = *(const v8s*)(PH + b0o);
      v8s B0l = *(const v8s*)(PL + b0o);
      v8s B1h = *(const v8s*)(PH + b1o);
      v8s B1l = *(const v8s*)(PL + b1o);
      acc[2*pp]   = __builtin_amdgcn_mfma_f32_32x32x16_bf16(Ah, B0h, acc[2*pp],   0, 0, 0);
      acc[2*pp+1] = __builtin_amdgcn_mfma_f32_32x32x16_bf16(Ah, B1h, acc[2*pp+1], 0, 0, 0);
      acc[2*pp]   = __builtin_amdgcn_mfma_f32_32x32x16_bf16(Ah, B0l, acc[2*pp],   0, 0, 0);
      acc[2*pp+1] = __builtin_amdgcn_mfma_f32_32x32x16_bf16(Ah, B1l, acc[2*pp+1], 0, 0, 0);
      acc[2*pp]   = __builtin_amdgcn_mfma_f32_32x32x16_bf16(Al, B0h, acc[2*pp],   0, 0, 0);
      acc[2*pp+1] = __builtin_amdgcn_mfma_f32_32x32x16_bf16(Al, B1h, acc[2*pp+1], 0, 0, 0);
      a += 512; b0o += 512; b1o += 512;
    }
  }

  #pragma unroll
  for (int h=0; h<2; h++){
    // ---- write rows [16h,16h+16) of the tile into LDS with neg_d epilogue ----
    #pragma unroll
    for (int pp=0; pp<2; pp++){
      int pair = wave*2 + pp;
      int c0 = pair*64 + (l & 31), c1 = c0 + 32;
      float xc0 = xxb[c0], xc1 = xxb[c1];
      #pragma unroll
      for (int r = 0; r < 8; r++){
        int rr = h*8 + r;
        int rl = (rr&3) + (((rr>>2)&1)<<3) + ((l>>5)<<2);  // 0..15
        float xr = xxb[rbase_local + h*16 + rl];
        Sl[rl][c0] = 2.f*acc[2*pp][rr]   - xr - xc0;
        Sl[rl][c1] = 2.f*acc[2*pp+1][rr] - xr - xc1;
      }
    }
    __syncthreads();
    // ---- exact top-20: 2 rows per wave, processed in parallel by half-waves ----
    {
      int hi = l >> 5;
      int li = l & 31;
      int rloc = wave*2 + hi;
      int grow = rb*32 + h*16 + rloc;
      int out_base = grow*20;
      unsigned long long hm = hi ? 0xFFFFFFFF00000000ull : 0x00000000FFFFFFFFull;

      // 32 values per lane; index m = li + 32*j (slot order == ascending index)
      unsigned kv[32];
      #pragma unroll
      for (int j=0;j<32;j++){
        unsigned u = __float_as_uint(Sl[rloc][li + 32*j]);
        kv[j] = (u & 0x80000000u) ? ~u : (u | 0x80000000u);
      }

      unsigned lmax = kv[0];
      #pragma unroll
      for (int j=1;j<32;j++) lmax = lmax > kv[j] ? lmax : kv[j];

      // tau = 20th-largest lane-max within this half (prefilter, >=20 survivors)
      unsigned tau = 0u;
      #pragma unroll
      for (int bit=31; bit>=0; --bit){
        unsigned cand = tau | (1u << bit);
        unsigned long long M = __ballot(lmax >= cand);
        int c = hi ? __popc((unsigned)(M >> 32)) : __popc((unsigned)M);
        tau = (c >= 20) ? cand : tau;        // per-lane cndmask, no branch
      }

      // compact survivors (value<<32 | index) into this row's scratch
      unsigned long long* sl = (unsigned long long*)&Sl[rloc][0];
      sl[li] = 0ull; sl[li+32] = 0ull;
      int b2 = 0;
      #pragma unroll
      for (int j=0;j<32;j++){
        bool p = kv[j] >= tau;
        unsigned long long M = __ballot(p) & hm;
        if (p){
          int s = b2 + lanecnt_below(M);
          if (s < 64) sl[s] = ((unsigned long long)kv[j] << 32) | (unsigned)(li + 32*j);
        }
        b2 += __popcll(M);
      }

      if (b2 <= 64){
        unsigned long long pk0 = sl[li], pk1 = sl[li+32];  // empty slots: key 0
        // exact 20th-largest among survivors
        unsigned vcur = 0u;
        #pragma unroll
        for (int bit=31; bit>=0; --bit){
          unsigned long long cc = (unsigned long long)(vcur | (1u << bit)) << 32;
          unsigned long long B0 = __ballot(pk0 >= cc);
          unsigned long long B1 = __ballot(pk1 >= cc);
          int clo = __popc((unsigned)B0) + __popc((unsigned)B1);
          int chi = __popc((unsigned)(B0>>32)) + __popc((unsigned)(B1>>32));
          int c = hi ? chi : clo;
          vcur = (c >= 20) ? (vcur | (1u << bit)) : vcur;
        }
        unsigned k0 = (unsigned)(pk0 >> 32), k1 = (unsigned)(pk1 >> 32);
        unsigned long long G0 = __ballot(k0 > vcur) & hm;
        unsigned long long G1 = __ballot(k1 > vcur) & hm;
        int ng0 = __popcll(G0);
        int c1  = ng0 + __popcll(G1);
        if (k0 > vcur) idx[out_base + lanecnt_below(G0)] = (int)(pk0 & 0xffffffffu);
        if (k1 > vcur) idx[out_base + ng0 + lanecnt_below(G1)] = (int)(pk1 & 0xffffffffu);
        unsigned long long E0 = __ballot(k0 == vcur) & hm;
        unsigned long long E1 = __ballot(k1 == vcur) & hm;
        int ne0 = __popcll(E0);
        if (k0 == vcur){ int s = c1 + lanecnt_below(E0); if (s < 20) idx[out_base + s] = (int)(pk0 & 0xffffffffu); }
        if (k1 == vcur){ int s = c1 + ne0 + lanecnt_below(E1); if (s < 20) idx[out_base + s] = (int)(pk1 & 0xffffffffu); }
      } else {
        // rare (near-degenerate ties): exact search over all 1024 values
        unsigned cur = 0u;
        #pragma unroll 1
        for (int bit=31; bit>=0; --bit){
          unsigned cand = cur | (1u << bit);
          int lc = 0;
          #pragma unroll
          for (int j=0;j<32;j++) lc += (kv[j] >= cand) ? 1 : 0;
          #pragma unroll
          for (int off=1; off<32; off<<=1) lc += __shfl_xor(lc, off, 64);  // within-half sum
          cur = (lc >= 20) ? cand : cur;
        }
        int bse = 0;
        #pragma unroll 1
        for (int j=0;j<32;j++){
          unsigned long long Mg = __ballot(kv[j] > cur) & hm;
          if (kv[j] > cur){ int s = bse + lanecnt_below(Mg); idx[out_base + s] = li + 32*j; }
          bse += __popcll(Mg);
        }
        #pragma unroll 1
        for (int j=0;j<32;j++){
          unsigned long long Me = __ballot(kv[j] == cur) & hm;
          if (kv[j] == cur){ int s = bse + lanecnt_below(Me); if (s < 20) idx[out_base + s] = li + 32*j; }
          bse += __popcll(Me);
          if (bse >= 20) break;
        }
      }
    }
    __syncthreads();
  }
}

// ---------------- EMB combine via MFMA: EMB = lrelu(eg*(X3S3.ew^T)*inv + eb) --------
// 256 threads (4 waves); gw = blockIdx*4+wave covers (mt 0..511, pair 0..1); K=256.
__global__ __launch_bounds__(256) void k_emb(const unsigned short* __restrict__ PH,
    const unsigned short* __restrict__ PL, const unsigned short* __restrict__ PWH,
    const unsigned short* __restrict__ PWL, const float* __restrict__ eg,
    const float* __restrict__ eb, float* __restrict__ EMB){
  int w = threadIdx.x >> 6;
  int l = threadIdx.x & 63;
  int gw = blockIdx.x*4 + w;
  int mt = gw >> 1, pair = gw & 1;
  const int nkc = 16;
  size_t ao  = ((size_t)mt*nkc)*512 + l*8;
  size_t b0o = ((size_t)(pair*2)*nkc)*512 + l*8;
  size_t b1o = b0o + (size_t)nkc*512;
  v16f acc0, acc1;
  #pragma unroll
  for (int i=0;i<16;i++){ acc0[i] = 0.f; acc1[i] = 0.f; }
  for (int kc=0; kc<nkc; kc++){
    v8s Ah  = *(const v8s*)(PH + ao);
    v8s Al  = *(const v8s*)(PL + ao);
    v8s B0h = *(const v8s*)(PWH + b0o);
    v8s B0l = *(const v8s*)(PWL + b0o);
    v8s B1h = *(const v8s*)(PWH + b1o);
    v8s B1l = *(const v8s*)(PWL + b1o);
    acc0 = __builtin_amdgcn_mfma_f32_32x32x16_bf16(Ah, B0h, acc0, 0, 0, 0);
    acc1 = __builtin_amdgcn_mfma_f32_32x32x16_bf16(Ah, B1h, acc1, 0, 0, 0);
    acc0 = __builtin_amdgcn_mfma_f32_32x32x16_bf16(Ah, B0l, acc0, 0, 0, 0);
    acc1 = __builtin_amdgcn_mfma_f32_32x32x16_bf16(Ah, B1l, acc1, 0, 0, 0);
    acc0 = __builtin_amdgcn_mfma_f32_32x32x16_bf16(Al, B0h, acc0, 0, 0, 0);
    acc1 = __builtin_amdgcn_mfma_f32_32x32x16_bf16(Al, B1h, acc1, 0, 0, 0);
    ao += 512; b0o += 512; b1o += 512;
  }
  int rbase = mt*32;
  int c0 = pair*64 + (l & 31), c1 = c0 + 32;
  float g0 = eg[c0]*INV_SQRT1P, g1 = eg[c1]*INV_SQRT1P;
  float bb0 = eb[c0], bb1 = eb[c1];
  #pragma unroll
  for (int r=0;r<16;r++){
    int rl_ = (r&3) + ((r>>2)<<3) + ((l>>5)<<2);
    float* dst = EMB + (size_t)(rbase + rl_)*128;
    dst[c0] = lrelu(g0*acc0[r] + bb0);
    dst[c1] = lrelu(g1*acc1[r] + bb1);
  }
}

// ---------------- edge epilogue, multi-row blocks (256 threads) ----------------
__global__ __launch_bounds__(256) void k_edge(const float* __restrict__ Y, const int* __restrict__ idx,
    const float* __restrict__ g, const float* __restrict__ bias,
    float* __restrict__ out, int O, int ldo, int ooff){
  int rpb = 256/O;
  int rloc = threadIdx.x/O;
  int o = threadIdx.x - rloc*O;
  int row = blockIdx.x*rpb + rloc;
  int b = row >> 10;
  __shared__ int js[4][20];
  int nj = rpb*20;
  if (threadIdx.x < nj) js[threadIdx.x/20][threadIdx.x%20] = idx[(blockIdx.x*rpb)*20 + threadIdx.x];
  __syncthreads();
  int O2 = O*2;
  float y1c = Y[(size_t)row*O2 + o];
  float d   = Y[(size_t)row*O2 + O + o] - y1c;
  float sc  = g[o] * INV_SQRT1P;
  float bb  = bias[o];
  const float* Yb = Y + ((size_t)(b<<10))*O2;
  float best = -1e38f;
  #pragma unroll
  for (int k=0;k<20;k++){
    float f = sc * (Yb[(size_t)js[rloc][k]*O2 + o] + d) + bb;
    best = fmaxf(best, lrelu(f));
  }
  out[(size_t)row*ldo + ooff + o] = best;
}

// ---------------- attention (16 batches): fused mean + gc ----------------
__global__ __launch_bounds__(1024) void k_meangc(const float* __restrict__ emb,
     const float* __restrict__ att_w, float* __restrict__ gc){
  int b = blockIdx.x; int f = threadIdx.x & 127; int ny = threadIdx.x >> 7;
  const float* e = emb + ((size_t)(b<<10) + ny*128)*128 + f;
  float s = 0.f;
  for (int n=0;n<128;n++) s += e[n*128];
  __shared__ float red[8][128];
  __shared__ float mr[128];
  red[ny][f] = s;
  __syncthreads();
  if (ny == 0){
    float t = 0.f;
    #pragma unroll
    for (int i=0;i<8;i++) t += red[i][f];
    mr[f] = t * (1.0f/1024.0f);
  }
  __syncthreads();
  if (threadIdx.x < 128){
    int g = threadIdx.x;
    float s2 = 0.f;
    for (int ff=0; ff<128; ff++) s2 += mr[ff]*att_w[ff*128+g];
    gc[b*128+g] = tanhf(s2);
  }
}

// ---------------- sc: 4 rows per block (4 waves), same per-wave math ----------------
__global__ __launch_bounds__(256) void k_sc(const float* __restrict__ emb, const float* __restrict__ gc,
     float* __restrict__ sc, float* __restrict__ attout){
  int wave = threadIdx.x >> 6;
  int l = threadIdx.x & 63;
  int row = blockIdx.x*4 + wave;
  int b = row >> 10;
  const float* e  = emb + (size_t)row*128;
  const float* gb = gc + b*128;
  float p = e[l]*gb[l] + e[l+64]*gb[l+64];
  #pragma unroll
  for (int off=32; off>0; off>>=1) p += __shfl_xor(p, off, 64);
  if (l == 0){
    float s = 1.0f/(1.0f + expf(-p));
    sc[row] = s;
    attout[row] = s;
  }
}

__global__ __launch_bounds__(1024) void k_pool(const float* __restrict__ emb, const float* __restrict__ sc,
     float* __restrict__ ep){
  int b = blockIdx.x; int f = threadIdx.x & 127; int ny = threadIdx.x >> 7;
  const float* e  = emb + ((size_t)(b<<10) + ny*128)*128 + f;
  const float* sb = sc + (b<<10) + ny*128;
  float s = 0.f;
  for (int n=0;n<128;n++) s += e[n*128]*sb[n];
  __shared__ float red[8][128];
  red[ny][f] = s;
  __syncthreads();
  if (ny == 0){
    float t = 0.f;
    #pragma unroll
    for (int i=0;i<8;i++) t += red[i][f];
    ep[b*128+f] = t;
  }
}

// ---------------- tensor network scoring ----------------
__global__ __launch_bounds__(256) void k_tnet(const float* __restrict__ e1, const float* __restrict__ e2,
    const float* __restrict__ tn_w, const float* __restrict__ tn_wb, const float* __restrict__ tn_bias,
    float* __restrict__ tsout){
  int b = blockIdx.x; int t = threadIdx.x; int tt = t & 15; int fs = t >> 4;
  __shared__ float E1[128], E2[128], red[16][17];
  if (t < 128){ E1[t] = e1[b*128+t]; E2[t] = e2[b*128+t]; }
  __syncthreads();
  float acc = 0.f;
  for (int f = fs*8; f < fs*8+8; f++){
    const float* tw = tn_w + f*128*16 + tt;
    float partial = 0.f;
    for (int g=0; g<128; g++) partial += E2[g]*tw[g*16];
    acc += E1[f]*partial;
  }
  red[fs][tt] = acc;
  __syncthreads();
  if (t < 16){
    float s = 0.f;
    #pragma unroll
    for (int i=0;i<16;i++) s += red[i][t];
    float acc2 = 0.f;
    for (int c=0;c<128;c++) acc2 += tn_wb[t*256+c]*E1[c] + tn_wb[t*256+128+c]*E2[c];
    float v = s + acc2 + tn_bias[t];
    tsout[b*16+t] = v > 0.f ? v : 0.f;
  }
}

__global__ __launch_bounds__(128) void k_score2(const float* __restrict__ ts,
   const float* __restrict__ fc1_w, const float* __restrict__ fc1_b,
   const float* __restrict__ sc_w, const float* __restrict__ sc_b, float* __restrict__ out){
  int t = threadIdx.x; int b = t >> 4, i = t & 15;
  __shared__ float h2[8][17];
  float a = 0.f;
  #pragma unroll
  for (int k=0;k<16;k++) a += ts[b*16+k]*fc1_w[i*16+k];
  a += fc1_b[i];
  h2[b][i] = a > 0.f ? a : 0.f;
  __syncthreads();
  if (t < 8){
    float s = 0.f;
    #pragma unroll
    for (int k=0;k<16;k++) s += h2[t][k]*sc_w[k];
    s += sc_b[0];
    out[t] = 1.0f/(1.0f + expf(-s));
  }
}

extern "C" void kernel_launch(void* const* d_in, const int* in_sizes, int n_in,
                              void* d_out, int out_size, void* d_ws, size_t ws_size,
                              hipStream_t stream){
  const float* f1  = (const float*)d_in[0];
  const float* f2  = (const float*)d_in[1];
  const float* sw1 = (const float*)d_in[2];  const float* sg1 = (const float*)d_in[3];  const float* sb1 = (const float*)d_in[4];
  const float* fw1 = (const float*)d_in[5];  const float* fg1 = (const float*)d_in[6];  const float* fb1 = (const float*)d_in[7];
  const float* sw2 = (const float*)d_in[8];  const float* sg2 = (const float*)d_in[9];  const float* sb2 = (const float*)d_in[10];
  const float* fw2 = (const float*)d_in[11]; const float* fg2 = (const float*)d_in[12]; const float* fb2 = (const float*)d_in[13];
  const float* sw3 = (const float*)d_in[14]; const float* sg3 = (const float*)d_in[15]; const float* sb3 = (const float*)d_in[16];
  const float* fw3 = (const float*)d_in[17]; const float* fg3 = (const float*)d_in[18]; const float* fb3 = (const float*)d_in[19];
  const float* ew  = (const float*)d_in[20]; const float* eg  = (const float*)d_in[21]; const float* eb  = (const float*)d_in[22];
  const float* att_w   = (const float*)d_in[23];
  const float* tn_w    = (const float*)d_in[24];
  const float* tn_wb   = (const float*)d_in[25];
  const float* tn_bias = (const float*)d_in[26];
  const float* fc1_w   = (const float*)d_in[27];
  const float* fc1_b   = (const float*)d_in[28];
  const float* sc_w    = (const float*)d_in[29];
  const float* sc_b    = (const float*)d_in[30];

  float* W    = (float*)d_ws;
  float* T0   = W;                  // 2,097,152  (16384 x <=128)
  float* T1   = W + 2097152;        // 2,097,152
  float* X3S3 = W + 4194304;        // 4,194,304  (16384 x 256)
  float* EMB  = W + 8388608;        // 2,097,152  (16384 x 128)
  float* xx   = W + 10485760;       // 16384
  float* gcb  = W + 10504192;       // 2048
  float* scb  = W + 10506240;       // 16384
  float* ep   = W + 10522624;       // 2048
  float* tsb  = W + 10524672;       // 128
  int*   idxb = (int*)(W + 10524800);            // 327680 ints
  unsigned short* PH = (unsigned short*)(W + 10852480); // packed frags hi (1M floats)
  unsigned short* PL = (unsigned short*)(W + 11901056); // packed frags lo (1M floats)
  unsigned short* PWH = (unsigned short*)(W + 12949632); // packed weight hi (16K floats)
  unsigned short* PWL = (unsigned short*)(W + 12966016); // packed weight lo (16K floats)
  float* REG  = W + 12982400;       // Y (<= 4M floats)
  unsigned short* PH2 = (unsigned short*)(W + 17176704); // packed X3S3 hi (2M floats)
  unsigned short* PL2 = (unsigned short*)(W + 19273856); // packed X3S3 lo (2M floats)

  (void)ws_size;
  float* out = (float*)d_out;

  auto edge = [&](const float* xin, int C, int O,
                  const float* w, const float* g, const float* bb,
                  float* xout, int ldo, int ooff){
    int Kp = (C + 15) & ~15;
    int nkc = Kp >> 4;
    int npair = 2*O/64;
    int nwblk = ((2*O/32)*nkc*64 + 255)/256;
    int nymf  = 64*npair;
    k_pw<<<nwblk + 128*nkc, 256, 0, stream>>>(xin, PH, PL, xx, w, PWH, PWL,
        C, Kp, O, nwblk, 2*O, 1, 1);
    k_dy<<<nymf + 512, 512, 0, stream>>>(PH, PL, PWH, PWL, xx, idxb, REG, Kp, 2*O, npair, nymf);
    k_edge<<<16384/(256/O), 256, 0, stream>>>(REG, idxb, g, bb, xout, O, ldo, ooff);
  };

  // xyz path (both point clouds as batches 0-7 / 8-15), one launch
  k_ext3<<<(2*8*3*1024+255)/256, 256, 0, stream>>>(f1, f2, T0);
  edge(T0, 3,   64, sw1, sg1, sb1, T1, 64, 0);
  edge(T1, 64,  64, sw2, sg2, sb2, T0, 64, 0);
  edge(T0, 64, 128, sw3, sg3, sb3, X3S3, 256, 0);    // x3 -> cols 0..127
  // sem path: LDS-transpose extract, both inputs, one launch
  k_extT<<<1024, 256, 0, stream>>>(f1, f2, T0);
  edge(T0, 128, 64, fw1, fg1, fb1, T1, 64, 0);
  edge(T1, 64,  64, fw2, fg2, fb2, T0, 64, 0);
  edge(T0, 64, 128, fw3, fg3, fb3, X3S3, 256, 128);  // s3 -> cols 128..255
  // combine via MFMA: pack X3S3 (K=256) + ew (128x256, plain layout), then GEMM+epilogue
  {
    int nwblk = ((128/32)*16*64 + 255)/256;          // 16
    k_pw<<<nwblk + 128*16, 256, 0, stream>>>(X3S3, PH2, PL2, xx, ew, PWH, PWL,
        256, 256, 128, nwblk, 128, 0, 0);
    k_emb<<<256, 256, 0, stream>>>(PH2, PL2, PWH, PWL, eg, eb, EMB);
  }
  // attention over all 16 batches
  k_meangc<<<16, 1024, 0, stream>>>(EMB, att_w, gcb);
  k_sc<<<4096, 256, 0, stream>>>(EMB, gcb, scb, out + 8);
  k_pool<<<16, 1024, 0, stream>>>(EMB, scb, ep);

  k_tnet<<<8, 256, 0, stream>>>(ep, ep + 1024, tn_w, tn_wb, tn_bias, tsb);
  k_score2<<<1, 128, 0, stream>>>(tsb, fc1_w, fc1_b, sc_w, sc_b, out);
}